// Round 7
// baseline (179.009 us; speedup 1.0000x reference)
//
#include <hip/hip_runtime.h>

#define NN 50000
#define NE 1600000
#define DF 64
#define DH 128

#define NB 782            // buckets of 64 rows: bucket = r >> 6
#define PB_EDGES 4096     // edges per k_part block
#define CAP 4096          // per-chunk edge capacity in k_agg (mean 2046, sd ~45)

// ws layout (bytes):
//   cnt    : int[NB+2]       @ 0
//   start  : int[NB+2]       @ 4096
//   cursor : int[NB+2]       @ 8192
//   colc   : ushort[NE]      @ 12288     (3,200,000 B)
//   rloc   : uchar[NE]       @ 3,212,288 (1,600,000 B)
//   xb     : ushort[NN*DF]   @ 4,812,288 (6,400,000 B)
// total 11,212,288 B < ws budget (11.2 MB proven round 5/6)

__device__ __forceinline__ unsigned short f2bf(float f) {
    unsigned u = __float_as_uint(f);
    unsigned r = (u + 0x7FFFu + ((u >> 16) & 1u)) >> 16;  // RNE
    return (unsigned short)r;
}

// ---------- cast x (f32) -> xb (bf16 raw) ----------
__global__ __launch_bounds__(256) void k_cast(const float* __restrict__ x,
                                              ushort* __restrict__ xb) {
    unsigned i = blockIdx.x * 256u + threadIdx.x;
    if (i >= NN * DF / 4) return;
    float4 v = ((const float4*)x)[i];
    ushort4 o;
    o.x = f2bf(v.x); o.y = f2bf(v.y); o.z = f2bf(v.z); o.w = f2bf(v.w);
    ((ushort4*)xb)[i] = o;
}

// ---------- bucket histogram (LDS-staged, native int atomics) ----------
__global__ __launch_bounds__(256) void k_hist(const int* __restrict__ ei,
                                              int* __restrict__ cnt) {
    __shared__ int h[784];
    for (int i = threadIdx.x; i < 784; i += 256) h[i] = 0;
    __syncthreads();
    for (unsigned e = blockIdx.x * 256u + threadIdx.x; e < NE; e += 512u * 256u) {
        int r = ei[e];
        int c = ei[NE + e];
        if (r != c) atomicAdd(&h[r >> 6], 1);
    }
    __syncthreads();
    for (int i = threadIdx.x; i < NB; i += 256)
        if (h[i]) atomicAdd(&cnt[i], h[i]);
}

// ---------- exclusive scan of NB bucket counts (1 wave) ----------
__global__ __launch_bounds__(64) void k_scan2(const int* __restrict__ cnt,
                                              int* __restrict__ start,
                                              int* __restrict__ cursor) {
    const int lane = threadIdx.x;
    int run = 0;
    for (int base = 0; base < 832; base += 64) {
        int i = base + lane;
        int v = (i < NB) ? cnt[i] : 0;
        int s = v;
#pragma unroll
        for (int off = 1; off < 64; off <<= 1) {
            int y = __shfl_up(s, off, 64);
            if (lane >= off) s += y;
        }
        int excl = run + s - v;
        if (i < NB + 1) { start[i] = excl; cursor[i] = excl; }
        run += __shfl(s, 63, 64);
    }
}

// ---------- partition: bucket the edges with block-level reservation ----------
__global__ __launch_bounds__(256) void k_part(const int* __restrict__ ei,
                                              int* __restrict__ cursor,
                                              ushort* __restrict__ colc,
                                              unsigned char* __restrict__ rloc) {
    __shared__ int lhist[784];
    __shared__ int lbase[784];
    const int tid = threadIdx.x;
    const int e0 = blockIdx.x * PB_EDGES;

    for (int i = tid; i < 784; i += 256) lhist[i] = 0;
    __syncthreads();

    int rr[16], cc[16], bk[16], val[16];
#pragma unroll
    for (int k = 0; k < 16; ++k) {
        int e = e0 + k * 256 + tid;
        int ok = (e < NE);
        int idx = ok ? e : 0;
        int r = ei[idx];
        int c = ei[NE + idx];
        int v = ok && (r != c);
        rr[k] = r; cc[k] = c; bk[k] = r >> 6; val[k] = v;
        if (v) atomicAdd(&lhist[bk[k]], 1);
    }
    __syncthreads();

    for (int b = tid; b < NB; b += 256) {
        int n = lhist[b];
        lbase[b] = (n > 0) ? atomicAdd(&cursor[b], n) : 0;
    }
    __syncthreads();
    for (int i = tid; i < 784; i += 256) lhist[i] = 0;  // reuse as local cursor
    __syncthreads();

#pragma unroll
    for (int k = 0; k < 16; ++k) {
        if (val[k]) {
            int off = atomicAdd(&lhist[bk[k]], 1);
            int pos = lbase[bk[k]] + off;
            colc[pos] = (unsigned short)cc[k];
            rloc[pos] = (unsigned char)(rr[k] & 63);
        }
    }
}

// ---------- aggregate: one block per 64-row bucket; LDS counting-sort by row,
// register accumulation, 2 features/lane, 2 edges/wave in flight ----------
__global__ __launch_bounds__(512) void k_agg(const float* __restrict__ x,
                                             const ushort* __restrict__ xb,
                                             const int* __restrict__ start,
                                             const ushort* __restrict__ colc,
                                             const unsigned char* __restrict__ rloc,
                                             const float* __restrict__ eps,
                                             float* __restrict__ out) {
    __shared__ int hist[64];
    __shared__ int rs[65];
    __shared__ int curs[64];
    __shared__ ushort scol[CAP];    // 8 KB

    const int tid = threadIdx.x;
    const int b = blockIdx.x;
    const int w = tid >> 6;         // wave 0..7
    const int lane = tid & 63;
    const int h = lane >> 5;        // half: which edge of the pair
    const int fp = lane & 31;       // feature pair -> features 2fp, 2fp+1
    const int s = start[b], e = start[b + 1];

    float ax[8], ay[8];
#pragma unroll
    for (int jp = 0; jp < 8; ++jp) { ax[jp] = 0.f; ay[jp] = 0.f; }

    for (int cs0 = s; cs0 < e; cs0 += CAP) {
        const int m = min(e - cs0, CAP);

        if (tid < 64) hist[tid] = 0;
        __syncthreads();

        for (int i = tid; i < m; i += 512)
            atomicAdd(&hist[rloc[cs0 + i]], 1);
        __syncthreads();

        if (tid < 64) {
            int v = hist[tid];
            int p = v;
#pragma unroll
            for (int off = 1; off < 64; off <<= 1) {
                int y = __shfl_up(p, off, 64);
                if (tid >= off) p += y;
            }
            rs[tid] = p - v;
            curs[tid] = p - v;
            if (tid == 63) rs[64] = p;
        }
        __syncthreads();

        for (int i = tid; i < m; i += 512) {
            int r = rloc[cs0 + i];
            int p = atomicAdd(&curs[r], 1);
            scol[p] = colc[cs0 + i];
        }
        __syncthreads();

        // wave w accumulates rows w*8 .. w*8+7; lane covers features 2fp,2fp+1;
        // halves h=0/1 take alternating edges of each pair.
#pragma unroll
        for (int jp = 0; jp < 8; ++jp) {
            const int rl = w * 8 + jp;
            int k = rs[rl];
            const int kend = rs[rl + 1];
            float sx = 0.f, sy = 0.f;
            for (; k + 4 <= kend; k += 4) {
                int c0 = scol[k + h];
                int c1 = scol[k + 2 + h];
                unsigned u0 = *(const unsigned*)(xb + (size_t)c0 * DF + 2 * fp);
                unsigned u1 = *(const unsigned*)(xb + (size_t)c1 * DF + 2 * fp);
                sx += __uint_as_float(u0 << 16);
                sy += __uint_as_float(u0 & 0xffff0000u);
                sx += __uint_as_float(u1 << 16);
                sy += __uint_as_float(u1 & 0xffff0000u);
            }
            for (; k < kend; k += 2) {
                int idx = k + h;
                if (idx < kend) {
                    int c = scol[idx];
                    unsigned u = *(const unsigned*)(xb + (size_t)c * DF + 2 * fp);
                    sx += __uint_as_float(u << 16);
                    sy += __uint_as_float(u & 0xffff0000u);
                }
            }
            ax[jp] += sx;
            ay[jp] += sy;
        }
        __syncthreads();
    }

    // combine halves and write out = (1+eps)*x + agg
    const float ev = 1.0f + eps[0];
    const int row0 = b << 6;
#pragma unroll
    for (int jp = 0; jp < 8; ++jp) {
        float tx = ax[jp] + __shfl_xor(ax[jp], 32, 64);
        float ty = ay[jp] + __shfl_xor(ay[jp], 32, 64);
        const int row = row0 + w * 8 + jp;
        if (((jp & 1) == h) && row < NN) {
            float2 xv = *(const float2*)(x + (size_t)row * DF + 2 * fp);
            float2 o;
            o.x = ev * xv.x + tx;
            o.y = ev * xv.y + ty;
            *(float2*)(out + (size_t)row * DF + 2 * fp) = o;
        }
    }
}

// ---------- fused MLP (unchanged, proven) ----------
#define ROWS 16
#define IN_STRIDE 68
#define H_STRIDE 132

__global__ __launch_bounds__(256) void k_mlp(float* io,
                                             const float* __restrict__ w1,
                                             const float* __restrict__ b1,
                                             const float* __restrict__ w2,
                                             const float* __restrict__ b2) {
    __shared__ float w1s[DF * DH];
    __shared__ float w2s[DH * DF];
    __shared__ float in_s[ROWS * IN_STRIDE];
    __shared__ float h_s[ROWS * H_STRIDE];

    const int tid = threadIdx.x;
    const int row0 = blockIdx.x * ROWS;

    for (int i = tid; i < DF * DH / 4; i += 256)
        ((float4*)w1s)[i] = ((const float4*)w1)[i];
    for (int i = tid; i < DH * DF / 4; i += 256)
        ((float4*)w2s)[i] = ((const float4*)w2)[i];

    {
        int r = tid >> 4, fq = tid & 15;
        float4 v = ((const float4*)io)[(size_t)(row0 + r) * 16 + fq];
        *(float4*)(in_s + r * IN_STRIDE + fq * 4) = v;
    }
    __syncthreads();

    {
        const int jb = tid & 31;
        const int rp = tid >> 5;
        const int j0 = jb * 4;
        const int rA = rp * 2, rB = rp * 2 + 1;
        float4 b1v = *(const float4*)&b1[j0];
        float aA0 = b1v.x, aA1 = b1v.y, aA2 = b1v.z, aA3 = b1v.w;
        float aB0 = b1v.x, aB1 = b1v.y, aB2 = b1v.z, aB3 = b1v.w;
        const float* inA = in_s + rA * IN_STRIDE;
        const float* inB = in_s + rB * IN_STRIDE;
#pragma unroll 8
        for (int ff = 0; ff < DF; ++ff) {
            float xa = inA[ff];
            float xbv = inB[ff];
            float4 w = *(const float4*)&w1s[ff * DH + j0];
            aA0 += xa * w.x; aA1 += xa * w.y; aA2 += xa * w.z; aA3 += xa * w.w;
            aB0 += xbv * w.x; aB1 += xbv * w.y; aB2 += xbv * w.z; aB3 += xbv * w.w;
        }
        float4 hA, hB;
        hA.x = fmaxf(aA0, 0.f); hA.y = fmaxf(aA1, 0.f);
        hA.z = fmaxf(aA2, 0.f); hA.w = fmaxf(aA3, 0.f);
        hB.x = fmaxf(aB0, 0.f); hB.y = fmaxf(aB1, 0.f);
        hB.z = fmaxf(aB2, 0.f); hB.w = fmaxf(aB3, 0.f);
        *(float4*)&h_s[rA * H_STRIDE + j0] = hA;
        *(float4*)&h_s[rB * H_STRIDE + j0] = hB;
    }
    __syncthreads();

    {
        const int r = tid >> 4;
        const int c0 = (tid & 15) * 4;
        float4 b2v = *(const float4*)&b2[c0];
        float a0 = b2v.x, a1 = b2v.y, a2 = b2v.z, a3 = b2v.w;
        const float* hr = h_s + r * H_STRIDE;
#pragma unroll 4
        for (int j4 = 0; j4 < DH / 4; ++j4) {
            float4 hv = *(const float4*)&hr[j4 * 4];
            float4 w0 = *(const float4*)&w2s[(j4 * 4 + 0) * DF + c0];
            float4 w1v = *(const float4*)&w2s[(j4 * 4 + 1) * DF + c0];
            float4 w2v = *(const float4*)&w2s[(j4 * 4 + 2) * DF + c0];
            float4 w3v = *(const float4*)&w2s[(j4 * 4 + 3) * DF + c0];
            a0 += hv.x * w0.x + hv.y * w1v.x + hv.z * w2v.x + hv.w * w3v.x;
            a1 += hv.x * w0.y + hv.y * w1v.y + hv.z * w2v.y + hv.w * w3v.y;
            a2 += hv.x * w0.z + hv.y * w1v.z + hv.z * w2v.z + hv.w * w3v.z;
            a3 += hv.x * w0.w + hv.y * w1v.w + hv.z * w2v.w + hv.w * w3v.w;
        }
        float4 o; o.x = a0; o.y = a1; o.z = a2; o.w = a3;
        *(float4*)&io[(size_t)(row0 + r) * DF + c0] = o;
    }
}

extern "C" void kernel_launch(void* const* d_in, const int* in_sizes, int n_in,
                              void* d_out, int out_size, void* d_ws, size_t ws_size,
                              hipStream_t stream) {
    const float* x   = (const float*)d_in[0];
    const int*   ei  = (const int*)d_in[1];
    const float* w1  = (const float*)d_in[2];
    const float* b1  = (const float*)d_in[3];
    const float* w2  = (const float*)d_in[4];
    const float* b2  = (const float*)d_in[5];
    const float* eps = (const float*)d_in[6];
    float* out = (float*)d_out;

    char* ws = (char*)d_ws;
    int*           cnt    = (int*)(ws + 0);
    int*           start  = (int*)(ws + 4096);
    int*           cursor = (int*)(ws + 8192);
    ushort*        colc   = (ushort*)(ws + 12288);
    unsigned char* rloc   = (unsigned char*)(ws + 3212288);
    ushort*        xb     = (ushort*)(ws + 4812288);

    hipMemsetAsync(cnt, 0, 4096, stream);

    k_cast<<<NN * DF / 4 / 256, 256, 0, stream>>>(x, xb);
    k_hist<<<512, 256, 0, stream>>>(ei, cnt);
    k_scan2<<<1, 64, 0, stream>>>(cnt, start, cursor);
    k_part<<<(NE + PB_EDGES - 1) / PB_EDGES, 256, 0, stream>>>(ei, cursor, colc, rloc);
    k_agg<<<NB, 512, 0, stream>>>(x, xb, start, colc, rloc, eps, out);
    k_mlp<<<NN / ROWS, 256, 0, stream>>>(out, w1, b1, w2, b2);
}

// Round 8
// 146.505 us; speedup vs baseline: 1.2219x; 1.2219x over previous
//
#include <hip/hip_runtime.h>

#define NN 50000
#define NE 1600000
#define DF 64
#define DH 128

#define NB 391            // buckets of 128 rows: bucket = r >> 7
#define PB_EDGES 16384    // edges per k_part block (1024 thr x 16)
#define CAP 6144          // per-chunk edge capacity in k_agg (mean 4092, sd ~64)

// ws layout (bytes):
//   cnt    : int[392]        @ 0         (zeroed each call)
//   start  : int[392]        @ 2048
//   cursor : int[392]        @ 4096
//   colc   : ushort[NE]      @ 6144      (3,200,000 B)
//   rloc   : uchar[NE]       @ 3,206,144 (1,600,000 B)
//   xb     : ushort[NN*DF]   @ 4,806,656 (6,400,000 B)
// total 11,206,656 B (proven budget)

__device__ __forceinline__ unsigned short f2bf(float f) {
    unsigned u = __float_as_uint(f);
    unsigned r = (u + 0x7FFFu + ((u >> 16) & 1u)) >> 16;  // RNE
    return (unsigned short)r;
}
__device__ __forceinline__ float bf2f(unsigned short h) {
    return __uint_as_float((unsigned)h << 16);
}

// ---------- cast x (f32) -> xb (bf16 raw) ----------
__global__ __launch_bounds__(256) void k_cast(const float* __restrict__ x,
                                              ushort* __restrict__ xb) {
    unsigned i = blockIdx.x * 256u + threadIdx.x;
    if (i >= NN * DF / 4) return;
    float4 v = ((const float4*)x)[i];
    ushort4 o;
    o.x = f2bf(v.x); o.y = f2bf(v.y); o.z = f2bf(v.z); o.w = f2bf(v.w);
    ((ushort4*)xb)[i] = o;
}

// ---------- bucket histogram (LDS-staged, native int atomics) ----------
__global__ __launch_bounds__(256) void k_hist(const int* __restrict__ ei,
                                              int* __restrict__ cnt) {
    __shared__ int h[392];
    for (int i = threadIdx.x; i < 392; i += 256) h[i] = 0;
    __syncthreads();
    for (unsigned e = blockIdx.x * 256u + threadIdx.x; e < NE; e += 512u * 256u) {
        int r = ei[e];
        int c = ei[NE + e];
        if (r != c) atomicAdd(&h[r >> 7], 1);
    }
    __syncthreads();
    for (int i = threadIdx.x; i < NB; i += 256)
        if (h[i]) atomicAdd(&cnt[i], h[i]);
}

// ---------- exclusive scan of 391 bucket counts (1 wave) ----------
__global__ __launch_bounds__(64) void k_scan2(const int* __restrict__ cnt,
                                              int* __restrict__ start,
                                              int* __restrict__ cursor) {
    const int lane = threadIdx.x;
    int run = 0;
    for (int base = 0; base < 448; base += 64) {
        int i = base + lane;
        int v = (i < NB) ? cnt[i] : 0;
        int s = v;
#pragma unroll
        for (int off = 1; off < 64; off <<= 1) {
            int y = __shfl_up(s, off, 64);
            if (lane >= off) s += y;
        }
        int excl = run + s - v;
        if (i < NB + 1) { start[i] = excl; cursor[i] = excl; }
        run += __shfl(s, 63, 64);
    }
}

// ---------- partition: 16384 edges/block -> ~42-edge bucket runs ----------
__global__ __launch_bounds__(1024) void k_part(const int* __restrict__ ei,
                                               int* __restrict__ cursor,
                                               ushort* __restrict__ colc,
                                               unsigned char* __restrict__ rloc) {
    __shared__ int lhist[392];
    __shared__ int lbase[392];
    const int tid = threadIdx.x;
    const int e0 = blockIdx.x * PB_EDGES;

    for (int i = tid; i < 392; i += 1024) lhist[i] = 0;
    __syncthreads();

    int rr[16], cc[16], bk[16], val[16];
#pragma unroll
    for (int k = 0; k < 16; ++k) {
        int e = e0 + k * 1024 + tid;
        int ok = (e < NE);
        int idx = ok ? e : 0;
        int r = ei[idx];
        int c = ei[NE + idx];
        int v = ok && (r != c);
        rr[k] = r; cc[k] = c; bk[k] = r >> 7; val[k] = v;
        if (v) atomicAdd(&lhist[bk[k]], 1);
    }
    __syncthreads();

    for (int b = tid; b < NB; b += 1024) {
        int n = lhist[b];
        lbase[b] = (n > 0) ? atomicAdd(&cursor[b], n) : 0;
    }
    __syncthreads();
    for (int i = tid; i < 392; i += 1024) lhist[i] = 0;  // reuse as local cursor
    __syncthreads();

#pragma unroll
    for (int k = 0; k < 16; ++k) {
        if (val[k]) {
            int off = atomicAdd(&lhist[bk[k]], 1);
            int pos = lbase[bk[k]] + off;
            colc[pos] = (unsigned short)cc[k];
            rloc[pos] = (unsigned char)(rr[k] & 127);
        }
    }
}

// ---------- aggregate: one block per 128-row bucket; LDS counting-sort by row,
// register accumulation (proven round-6 structure, 8-deep gather pipeline) ----------
__global__ __launch_bounds__(1024) void k_agg(const float* __restrict__ x,
                                              const ushort* __restrict__ xb,
                                              const int* __restrict__ start,
                                              const ushort* __restrict__ colc,
                                              const unsigned char* __restrict__ rloc,
                                              const float* __restrict__ eps,
                                              float* __restrict__ out) {
    __shared__ int hist[128];
    __shared__ int rs[129];
    __shared__ int curs[128];
    __shared__ ushort scol[CAP];    // 12 KB

    const int tid = threadIdx.x;
    const int b = blockIdx.x;
    const int w = tid >> 6;         // wave 0..15
    const int f = tid & 63;         // feature lane
    const int s = start[b], e = start[b + 1];

    float a0 = 0.f, a1 = 0.f, a2 = 0.f, a3 = 0.f, a4 = 0.f, a5 = 0.f, a6 = 0.f, a7 = 0.f;

    for (int cs0 = s; cs0 < e; cs0 += CAP) {
        const int m = min(e - cs0, CAP);

        for (int i = tid; i < 128; i += 1024) { hist[i] = 0; }
        __syncthreads();

        for (int i = tid; i < m; i += 1024)
            atomicAdd(&hist[rloc[cs0 + i]], 1);
        __syncthreads();

        if (tid < 64) {
            int h0 = hist[2 * tid], h1 = hist[2 * tid + 1];
            int p = h0 + h1;
#pragma unroll
            for (int off = 1; off < 64; off <<= 1) {
                int y = __shfl_up(p, off, 64);
                if (tid >= off) p += y;
            }
            int excl = p - (h0 + h1);
            rs[2 * tid] = excl;
            rs[2 * tid + 1] = excl + h0;
            curs[2 * tid] = excl;
            curs[2 * tid + 1] = excl + h0;
            if (tid == 63) rs[128] = p;
        }
        __syncthreads();

        for (int i = tid; i < m; i += 1024) {
            int r = rloc[cs0 + i];
            int p = atomicAdd(&curs[r], 1);
            scol[p] = colc[cs0 + i];
        }
        __syncthreads();

        // register accumulation: wave w, row rl = w + jp*16, lane = feature
#pragma unroll
        for (int jp = 0; jp < 8; ++jp) {
            const int rl = w + jp * 16;
            int k = rs[rl];
            const int kend = rs[rl + 1];
            float acc = 0.f;
            for (; k + 8 <= kend; k += 8) {
                int c0 = scol[k],     c1 = scol[k + 1], c2 = scol[k + 2], c3 = scol[k + 3];
                int c4 = scol[k + 4], c5 = scol[k + 5], c6 = scol[k + 6], c7 = scol[k + 7];
                float v0 = bf2f(xb[(size_t)c0 * DF + f]);
                float v1 = bf2f(xb[(size_t)c1 * DF + f]);
                float v2 = bf2f(xb[(size_t)c2 * DF + f]);
                float v3 = bf2f(xb[(size_t)c3 * DF + f]);
                float v4 = bf2f(xb[(size_t)c4 * DF + f]);
                float v5 = bf2f(xb[(size_t)c5 * DF + f]);
                float v6 = bf2f(xb[(size_t)c6 * DF + f]);
                float v7 = bf2f(xb[(size_t)c7 * DF + f]);
                acc += v0; acc += v1; acc += v2; acc += v3;
                acc += v4; acc += v5; acc += v6; acc += v7;
            }
            for (; k + 4 <= kend; k += 4) {
                int c0 = scol[k], c1 = scol[k + 1], c2 = scol[k + 2], c3 = scol[k + 3];
                float v0 = bf2f(xb[(size_t)c0 * DF + f]);
                float v1 = bf2f(xb[(size_t)c1 * DF + f]);
                float v2 = bf2f(xb[(size_t)c2 * DF + f]);
                float v3 = bf2f(xb[(size_t)c3 * DF + f]);
                acc += v0; acc += v1; acc += v2; acc += v3;
            }
            for (; k < kend; ++k) acc += bf2f(xb[(size_t)scol[k] * DF + f]);
            if (jp == 0) a0 += acc; else if (jp == 1) a1 += acc;
            else if (jp == 2) a2 += acc; else if (jp == 3) a3 += acc;
            else if (jp == 4) a4 += acc; else if (jp == 5) a5 += acc;
            else if (jp == 6) a6 += acc; else a7 += acc;
        }
        __syncthreads();
    }

    // write out = (1+eps)*x + acc
    const float ev = 1.0f + eps[0];
    const int row0 = b << 7;
#pragma unroll
    for (int jp = 0; jp < 8; ++jp) {
        int row = row0 + w + jp * 16;
        if (row < NN) {
            float acc = (jp == 0) ? a0 : (jp == 1) ? a1 : (jp == 2) ? a2 : (jp == 3) ? a3
                       : (jp == 4) ? a4 : (jp == 5) ? a5 : (jp == 6) ? a6 : a7;
            out[(size_t)row * DF + f] = ev * x[(size_t)row * DF + f] + acc;
        }
    }
}

// ---------- fused MLP (unchanged, proven) ----------
#define ROWS 16
#define IN_STRIDE 68
#define H_STRIDE 132

__global__ __launch_bounds__(256) void k_mlp(float* io,
                                             const float* __restrict__ w1,
                                             const float* __restrict__ b1,
                                             const float* __restrict__ w2,
                                             const float* __restrict__ b2) {
    __shared__ float w1s[DF * DH];
    __shared__ float w2s[DH * DF];
    __shared__ float in_s[ROWS * IN_STRIDE];
    __shared__ float h_s[ROWS * H_STRIDE];

    const int tid = threadIdx.x;
    const int row0 = blockIdx.x * ROWS;

    for (int i = tid; i < DF * DH / 4; i += 256)
        ((float4*)w1s)[i] = ((const float4*)w1)[i];
    for (int i = tid; i < DH * DF / 4; i += 256)
        ((float4*)w2s)[i] = ((const float4*)w2)[i];

    {
        int r = tid >> 4, fq = tid & 15;
        float4 v = ((const float4*)io)[(size_t)(row0 + r) * 16 + fq];
        *(float4*)(in_s + r * IN_STRIDE + fq * 4) = v;
    }
    __syncthreads();

    {
        const int jb = tid & 31;
        const int rp = tid >> 5;
        const int j0 = jb * 4;
        const int rA = rp * 2, rB = rp * 2 + 1;
        float4 b1v = *(const float4*)&b1[j0];
        float aA0 = b1v.x, aA1 = b1v.y, aA2 = b1v.z, aA3 = b1v.w;
        float aB0 = b1v.x, aB1 = b1v.y, aB2 = b1v.z, aB3 = b1v.w;
        const float* inA = in_s + rA * IN_STRIDE;
        const float* inB = in_s + rB * IN_STRIDE;
#pragma unroll 8
        for (int ff = 0; ff < DF; ++ff) {
            float xa = inA[ff];
            float xbv = inB[ff];
            float4 w = *(const float4*)&w1s[ff * DH + j0];
            aA0 += xa * w.x; aA1 += xa * w.y; aA2 += xa * w.z; aA3 += xa * w.w;
            aB0 += xbv * w.x; aB1 += xbv * w.y; aB2 += xbv * w.z; aB3 += xbv * w.w;
        }
        float4 hA, hB;
        hA.x = fmaxf(aA0, 0.f); hA.y = fmaxf(aA1, 0.f);
        hA.z = fmaxf(aA2, 0.f); hA.w = fmaxf(aA3, 0.f);
        hB.x = fmaxf(aB0, 0.f); hB.y = fmaxf(aB1, 0.f);
        hB.z = fmaxf(aB2, 0.f); hB.w = fmaxf(aB3, 0.f);
        *(float4*)&h_s[rA * H_STRIDE + j0] = hA;
        *(float4*)&h_s[rB * H_STRIDE + j0] = hB;
    }
    __syncthreads();

    {
        const int r = tid >> 4;
        const int c0 = (tid & 15) * 4;
        float4 b2v = *(const float4*)&b2[c0];
        float a0 = b2v.x, a1 = b2v.y, a2 = b2v.z, a3 = b2v.w;
        const float* hr = h_s + r * H_STRIDE;
#pragma unroll 4
        for (int j4 = 0; j4 < DH / 4; ++j4) {
            float4 hv = *(const float4*)&hr[j4 * 4];
            float4 w0 = *(const float4*)&w2s[(j4 * 4 + 0) * DF + c0];
            float4 w1v = *(const float4*)&w2s[(j4 * 4 + 1) * DF + c0];
            float4 w2v = *(const float4*)&w2s[(j4 * 4 + 2) * DF + c0];
            float4 w3v = *(const float4*)&w2s[(j4 * 4 + 3) * DF + c0];
            a0 += hv.x * w0.x + hv.y * w1v.x + hv.z * w2v.x + hv.w * w3v.x;
            a1 += hv.x * w0.y + hv.y * w1v.y + hv.z * w2v.y + hv.w * w3v.y;
            a2 += hv.x * w0.z + hv.y * w1v.z + hv.z * w2v.z + hv.w * w3v.z;
            a3 += hv.x * w0.w + hv.y * w1v.w + hv.z * w2v.w + hv.w * w3v.w;
        }
        float4 o; o.x = a0; o.y = a1; o.z = a2; o.w = a3;
        *(float4*)&io[(size_t)(row0 + r) * DF + c0] = o;
    }
}

extern "C" void kernel_launch(void* const* d_in, const int* in_sizes, int n_in,
                              void* d_out, int out_size, void* d_ws, size_t ws_size,
                              hipStream_t stream) {
    const float* x   = (const float*)d_in[0];
    const int*   ei  = (const int*)d_in[1];
    const float* w1  = (const float*)d_in[2];
    const float* b1  = (const float*)d_in[3];
    const float* w2  = (const float*)d_in[4];
    const float* b2  = (const float*)d_in[5];
    const float* eps = (const float*)d_in[6];
    float* out = (float*)d_out;

    char* ws = (char*)d_ws;
    int*           cnt    = (int*)(ws + 0);
    int*           start  = (int*)(ws + 2048);
    int*           cursor = (int*)(ws + 4096);
    ushort*        colc   = (ushort*)(ws + 6144);
    unsigned char* rloc   = (unsigned char*)(ws + 3206144);
    ushort*        xb     = (ushort*)(ws + 4806656);

    hipMemsetAsync(cnt, 0, 2048, stream);

    k_cast<<<NN * DF / 4 / 256, 256, 0, stream>>>(x, xb);
    k_hist<<<512, 256, 0, stream>>>(ei, cnt);
    k_scan2<<<1, 64, 0, stream>>>(cnt, start, cursor);
    k_part<<<(NE + PB_EDGES - 1) / PB_EDGES, 1024, 0, stream>>>(ei, cursor, colc, rloc);
    k_agg<<<NB, 1024, 0, stream>>>(x, xb, start, colc, rloc, eps, out);
    k_mlp<<<NN / ROWS, 256, 0, stream>>>(out, w1, b1, w2, b2);
}

// Round 9
// 124.041 us; speedup vs baseline: 1.4431x; 1.1811x over previous
//
#include <hip/hip_runtime.h>

#define NN 50000
#define NE 1600000
#define DF 64
#define DH 128

#define NB 391            // buckets of 128 rows: bucket = r >> 7
#define PB_EDGES 16384    // edges per k_part block (1024 thr x 16)
#define CAP 6144          // per-chunk edge capacity in k_agg

// ws layout (bytes):
//   cnt    : int[392]        @ 0         (zeroed each call)
//   start  : int[392]        @ 2048
//   cursor : int[392]        @ 4096
//   colc   : ushort[NE]      @ 6144      (3,200,000 B)
//   rloc   : uchar[NE]       @ 3,206,144 (1,600,000 B)
//   xb     : ushort[NN*DF]   @ 4,806,656 (6,400,000 B)

typedef __attribute__((ext_vector_type(8))) short bf16x8;
typedef __attribute__((ext_vector_type(4))) float f32x4;

__device__ __forceinline__ unsigned short f2bf(float f) {
    unsigned u = __float_as_uint(f);
    unsigned r = (u + 0x7FFFu + ((u >> 16) & 1u)) >> 16;  // RNE
    return (unsigned short)r;
}
__device__ __forceinline__ float bf2f(unsigned short h) {
    return __uint_as_float((unsigned)h << 16);
}

// ---------- cast x (f32) -> xb (bf16 raw) ----------
__global__ __launch_bounds__(256) void k_cast(const float* __restrict__ x,
                                              ushort* __restrict__ xb) {
    unsigned i = blockIdx.x * 256u + threadIdx.x;
    if (i >= NN * DF / 4) return;
    float4 v = ((const float4*)x)[i];
    ushort4 o;
    o.x = f2bf(v.x); o.y = f2bf(v.y); o.z = f2bf(v.z); o.w = f2bf(v.w);
    ((ushort4*)xb)[i] = o;
}

// ---------- bucket histogram (LDS-staged, native int atomics) ----------
__global__ __launch_bounds__(256) void k_hist(const int* __restrict__ ei,
                                              int* __restrict__ cnt) {
    __shared__ int h[392];
    for (int i = threadIdx.x; i < 392; i += 256) h[i] = 0;
    __syncthreads();
    for (unsigned e = blockIdx.x * 256u + threadIdx.x; e < NE; e += 512u * 256u) {
        int r = ei[e];
        int c = ei[NE + e];
        if (r != c) atomicAdd(&h[r >> 7], 1);
    }
    __syncthreads();
    for (int i = threadIdx.x; i < NB; i += 256)
        if (h[i]) atomicAdd(&cnt[i], h[i]);
}

// ---------- exclusive scan of 391 bucket counts (1 wave) ----------
__global__ __launch_bounds__(64) void k_scan2(const int* __restrict__ cnt,
                                              int* __restrict__ start,
                                              int* __restrict__ cursor) {
    const int lane = threadIdx.x;
    int run = 0;
    for (int base = 0; base < 448; base += 64) {
        int i = base + lane;
        int v = (i < NB) ? cnt[i] : 0;
        int s = v;
#pragma unroll
        for (int off = 1; off < 64; off <<= 1) {
            int y = __shfl_up(s, off, 64);
            if (lane >= off) s += y;
        }
        int excl = run + s - v;
        if (i < NB + 1) { start[i] = excl; cursor[i] = excl; }
        run += __shfl(s, 63, 64);
    }
}

// ---------- partition: 16384 edges/block -> ~42-edge bucket runs ----------
__global__ __launch_bounds__(1024) void k_part(const int* __restrict__ ei,
                                               int* __restrict__ cursor,
                                               ushort* __restrict__ colc,
                                               unsigned char* __restrict__ rloc) {
    __shared__ int lhist[392];
    __shared__ int lbase[392];
    const int tid = threadIdx.x;
    const int e0 = blockIdx.x * PB_EDGES;

    for (int i = tid; i < 392; i += 1024) lhist[i] = 0;
    __syncthreads();

    int rr[16], cc[16], bk[16], val[16];
#pragma unroll
    for (int k = 0; k < 16; ++k) {
        int e = e0 + k * 1024 + tid;
        int ok = (e < NE);
        int idx = ok ? e : 0;
        int r = ei[idx];
        int c = ei[NE + idx];
        int v = ok && (r != c);
        rr[k] = r; cc[k] = c; bk[k] = r >> 7; val[k] = v;
        if (v) atomicAdd(&lhist[bk[k]], 1);
    }
    __syncthreads();

    for (int b = tid; b < NB; b += 1024) {
        int n = lhist[b];
        lbase[b] = (n > 0) ? atomicAdd(&cursor[b], n) : 0;
    }
    __syncthreads();
    for (int i = tid; i < 392; i += 1024) lhist[i] = 0;  // reuse as local cursor
    __syncthreads();

#pragma unroll
    for (int k = 0; k < 16; ++k) {
        if (val[k]) {
            int off = atomicAdd(&lhist[bk[k]], 1);
            int pos = lbase[bk[k]] + off;
            colc[pos] = (unsigned short)cc[k];
            rloc[pos] = (unsigned char)(rr[k] & 127);
        }
    }
}

// ---------- aggregate: one block per 128-row bucket; LDS counting-sort by row,
// register accumulation (proven round-8 structure, 8-deep gather pipeline) ----------
__global__ __launch_bounds__(1024) void k_agg(const float* __restrict__ x,
                                              const ushort* __restrict__ xb,
                                              const int* __restrict__ start,
                                              const ushort* __restrict__ colc,
                                              const unsigned char* __restrict__ rloc,
                                              const float* __restrict__ eps,
                                              float* __restrict__ out) {
    __shared__ int hist[128];
    __shared__ int rs[129];
    __shared__ int curs[128];
    __shared__ ushort scol[CAP];    // 12 KB

    const int tid = threadIdx.x;
    const int b = blockIdx.x;
    const int w = tid >> 6;         // wave 0..15
    const int f = tid & 63;         // feature lane
    const int s = start[b], e = start[b + 1];

    float a0 = 0.f, a1 = 0.f, a2 = 0.f, a3 = 0.f, a4 = 0.f, a5 = 0.f, a6 = 0.f, a7 = 0.f;

    for (int cs0 = s; cs0 < e; cs0 += CAP) {
        const int m = min(e - cs0, CAP);

        for (int i = tid; i < 128; i += 1024) { hist[i] = 0; }
        __syncthreads();

        for (int i = tid; i < m; i += 1024)
            atomicAdd(&hist[rloc[cs0 + i]], 1);
        __syncthreads();

        if (tid < 64) {
            int h0 = hist[2 * tid], h1 = hist[2 * tid + 1];
            int p = h0 + h1;
#pragma unroll
            for (int off = 1; off < 64; off <<= 1) {
                int y = __shfl_up(p, off, 64);
                if (tid >= off) p += y;
            }
            int excl = p - (h0 + h1);
            rs[2 * tid] = excl;
            rs[2 * tid + 1] = excl + h0;
            curs[2 * tid] = excl;
            curs[2 * tid + 1] = excl + h0;
            if (tid == 63) rs[128] = p;
        }
        __syncthreads();

        for (int i = tid; i < m; i += 1024) {
            int r = rloc[cs0 + i];
            int p = atomicAdd(&curs[r], 1);
            scol[p] = colc[cs0 + i];
        }
        __syncthreads();

#pragma unroll
        for (int jp = 0; jp < 8; ++jp) {
            const int rl = w + jp * 16;
            int k = rs[rl];
            const int kend = rs[rl + 1];
            float acc = 0.f;
            for (; k + 8 <= kend; k += 8) {
                int c0 = scol[k],     c1 = scol[k + 1], c2 = scol[k + 2], c3 = scol[k + 3];
                int c4 = scol[k + 4], c5 = scol[k + 5], c6 = scol[k + 6], c7 = scol[k + 7];
                float v0 = bf2f(xb[(size_t)c0 * DF + f]);
                float v1 = bf2f(xb[(size_t)c1 * DF + f]);
                float v2 = bf2f(xb[(size_t)c2 * DF + f]);
                float v3 = bf2f(xb[(size_t)c3 * DF + f]);
                float v4 = bf2f(xb[(size_t)c4 * DF + f]);
                float v5 = bf2f(xb[(size_t)c5 * DF + f]);
                float v6 = bf2f(xb[(size_t)c6 * DF + f]);
                float v7 = bf2f(xb[(size_t)c7 * DF + f]);
                acc += v0; acc += v1; acc += v2; acc += v3;
                acc += v4; acc += v5; acc += v6; acc += v7;
            }
            for (; k + 4 <= kend; k += 4) {
                int c0 = scol[k], c1 = scol[k + 1], c2 = scol[k + 2], c3 = scol[k + 3];
                float v0 = bf2f(xb[(size_t)c0 * DF + f]);
                float v1 = bf2f(xb[(size_t)c1 * DF + f]);
                float v2 = bf2f(xb[(size_t)c2 * DF + f]);
                float v3 = bf2f(xb[(size_t)c3 * DF + f]);
                acc += v0; acc += v1; acc += v2; acc += v3;
            }
            for (; k < kend; ++k) acc += bf2f(xb[(size_t)scol[k] * DF + f]);
            if (jp == 0) a0 += acc; else if (jp == 1) a1 += acc;
            else if (jp == 2) a2 += acc; else if (jp == 3) a3 += acc;
            else if (jp == 4) a4 += acc; else if (jp == 5) a5 += acc;
            else if (jp == 6) a6 += acc; else a7 += acc;
        }
        __syncthreads();
    }

    const float ev = 1.0f + eps[0];
    const int row0 = b << 7;
#pragma unroll
    for (int jp = 0; jp < 8; ++jp) {
        int row = row0 + w + jp * 16;
        if (row < NN) {
            float acc = (jp == 0) ? a0 : (jp == 1) ? a1 : (jp == 2) ? a2 : (jp == 3) ? a3
                       : (jp == 4) ? a4 : (jp == 5) ? a5 : (jp == 6) ? a6 : a7;
            out[(size_t)row * DF + f] = ev * x[(size_t)row * DF + f] + acc;
        }
    }
}

// ---------- MFMA MLP: in(bf16) @ w1 -> relu -> @ w2, per-block 64 rows ----------
// Fragment layouts (m89-verified family): A row=l&15, k=(l>>4)*8+e;
// B col=l&15, k=(l>>4)*8+e; D col=l&15, row=(l>>4)*4+reg.
#define IN_LD 72      // elems; row stride 144 B (16B-aligned, 2-way banks)
#define W1_LD 72
#define W2_LD 136     // 272 B rows
#define H_LD 136

__global__ __launch_bounds__(256) void k_mlp(float* io,
                                             const float* __restrict__ w1,
                                             const float* __restrict__ b1,
                                             const float* __restrict__ w2,
                                             const float* __restrict__ b2) {
    __shared__ ushort in_s[64 * IN_LD];       //  9,216 B
    __shared__ ushort w1t_s[128 * W1_LD];     // 18,432 B  w1t[j][k]
    __shared__ ushort w2t_s[64 * W2_LD];      // 17,408 B  w2t[c][j]
    __shared__ ushort h_s[4 * 16 * H_LD];     // 17,408 B  per-wave [16][136]

    const int tid = threadIdx.x;
    const int m0 = blockIdx.x * 64;
    const int w = tid >> 6;
    const int lane = tid & 63;
    const int quad = lane >> 4;
    const int r16 = lane & 15;

    // stage w1 (64x128 f32) transposed -> w1t_s[j][k] bf16
#pragma unroll
    for (int t = 0; t < 8; ++t) {
        int i4 = t * 256 + tid;              // 2048 float4
        float4 v = ((const float4*)w1)[i4];
        int idx = i4 * 4;
        int k = idx >> 7, j = idx & 127;
        w1t_s[(j + 0) * W1_LD + k] = f2bf(v.x);
        w1t_s[(j + 1) * W1_LD + k] = f2bf(v.y);
        w1t_s[(j + 2) * W1_LD + k] = f2bf(v.z);
        w1t_s[(j + 3) * W1_LD + k] = f2bf(v.w);
    }
    // stage w2 (128x64 f32) transposed -> w2t_s[c][j] bf16
#pragma unroll
    for (int t = 0; t < 8; ++t) {
        int i4 = t * 256 + tid;
        float4 v = ((const float4*)w2)[i4];
        int idx = i4 * 4;
        int j = idx >> 6, c = idx & 63;
        w2t_s[(c + 0) * W2_LD + j] = f2bf(v.x);
        w2t_s[(c + 1) * W2_LD + j] = f2bf(v.y);
        w2t_s[(c + 2) * W2_LD + j] = f2bf(v.z);
        w2t_s[(c + 3) * W2_LD + j] = f2bf(v.w);
    }
    // stage 64 input rows -> bf16
#pragma unroll
    for (int t = 0; t < 4; ++t) {
        int i4 = t * 256 + tid;              // 1024 float4
        int row = i4 >> 4, fq = i4 & 15;
        float4 v = make_float4(0.f, 0.f, 0.f, 0.f);
        if (m0 + row < NN) v = ((const float4*)io)[(size_t)(m0 + row) * 16 + fq];
        ushort4 o;
        o.x = f2bf(v.x); o.y = f2bf(v.y); o.z = f2bf(v.z); o.w = f2bf(v.w);
        *(ushort4*)&in_s[row * IN_LD + fq * 4] = o;
    }
    __syncthreads();

    // ---- layer 1: H = relu(in @ w1 + b1), wave w owns rows w*16..+15 ----
    const ushort* inrow = in_s + (w * 16 + r16) * IN_LD + quad * 8;
    bf16x8 aA = *(const bf16x8*)(inrow);
    bf16x8 aB = *(const bf16x8*)(inrow + 32);

    ushort* hw = h_s + w * 16 * H_LD;        // wave-private

#pragma unroll
    for (int nt = 0; nt < 8; ++nt) {
        const ushort* bp = w1t_s + (nt * 16 + r16) * W1_LD + quad * 8;
        bf16x8 bA = *(const bf16x8*)(bp);
        bf16x8 bB = *(const bf16x8*)(bp + 32);
        f32x4 acc = {0.f, 0.f, 0.f, 0.f};
        acc = __builtin_amdgcn_mfma_f32_16x16x32_bf16(aA, bA, acc, 0, 0, 0);
        acc = __builtin_amdgcn_mfma_f32_16x16x32_bf16(aB, bB, acc, 0, 0, 0);
        float bias = b1[nt * 16 + r16];
#pragma unroll
        for (int reg = 0; reg < 4; ++reg) {
            float hv = fmaxf(acc[reg] + bias, 0.f);
            hw[(quad * 4 + reg) * H_LD + nt * 16 + r16] = f2bf(hv);
        }
    }
    // wave-private LDS RAW below: compiler inserts lgkmcnt wait (same wave)

    // ---- layer 2: out = H @ w2 + b2 ----
    f32x4 acc2[4];
#pragma unroll
    for (int ct = 0; ct < 4; ++ct) acc2[ct] = (f32x4){0.f, 0.f, 0.f, 0.f};
#pragma unroll
    for (int ks = 0; ks < 4; ++ks) {
        bf16x8 a2 = *(const bf16x8*)(hw + r16 * H_LD + quad * 8 + ks * 32);
#pragma unroll
        for (int ct = 0; ct < 4; ++ct) {
            bf16x8 b2f = *(const bf16x8*)(w2t_s + (ct * 16 + r16) * W2_LD + quad * 8 + ks * 32);
            acc2[ct] = __builtin_amdgcn_mfma_f32_16x16x32_bf16(a2, b2f, acc2[ct], 0, 0, 0);
        }
    }
#pragma unroll
    for (int ct = 0; ct < 4; ++ct) {
        int c = ct * 16 + r16;
        float bias = b2[c];
#pragma unroll
        for (int reg = 0; reg < 4; ++reg) {
            int m = m0 + w * 16 + quad * 4 + reg;
            if (m < NN) io[(size_t)m * DF + c] = acc2[ct][reg] + bias;
        }
    }
}

extern "C" void kernel_launch(void* const* d_in, const int* in_sizes, int n_in,
                              void* d_out, int out_size, void* d_ws, size_t ws_size,
                              hipStream_t stream) {
    const float* x   = (const float*)d_in[0];
    const int*   ei  = (const int*)d_in[1];
    const float* w1  = (const float*)d_in[2];
    const float* b1  = (const float*)d_in[3];
    const float* w2  = (const float*)d_in[4];
    const float* b2  = (const float*)d_in[5];
    const float* eps = (const float*)d_in[6];
    float* out = (float*)d_out;

    char* ws = (char*)d_ws;
    int*           cnt    = (int*)(ws + 0);
    int*           start  = (int*)(ws + 2048);
    int*           cursor = (int*)(ws + 4096);
    ushort*        colc   = (ushort*)(ws + 6144);
    unsigned char* rloc   = (unsigned char*)(ws + 3206144);
    ushort*        xb     = (ushort*)(ws + 4806656);

    hipMemsetAsync(cnt, 0, 2048, stream);

    k_cast<<<NN * DF / 4 / 256, 256, 0, stream>>>(x, xb);
    k_hist<<<512, 256, 0, stream>>>(ei, cnt);
    k_scan2<<<1, 64, 0, stream>>>(cnt, start, cursor);
    k_part<<<(NE + PB_EDGES - 1) / PB_EDGES, 1024, 0, stream>>>(ei, cursor, colc, rloc);
    k_agg<<<NB, 1024, 0, stream>>>(x, xb, start, colc, rloc, eps, out);
    k_mlp<<<(NN + 63) / 64, 256, 0, stream>>>(out, w1, b1, w2, b2);
}